// Round 1
// baseline (1296.837 us; speedup 1.0000x reference)
//
#include <hip/hip_runtime.h>
#include <math.h>

#define N_AGENTS 8
#define NHEADS 4
#define HYP 128
#define HD 32
#define EMB 32
#define ED 64
#define NE 32
#define NB 4096

// ws layout: per gslot (0 -> g=1, 1 -> g=3), stride 1024 floats:
//   [0:512)   vw2[hh][h']  (4 x 128)
//   [512:516) vb2[hh]
//   [516]     const = oc + cb
__global__ void prep_kernel(const float* __restrict__ qkv_w, const float* __restrict__ qkv_b,
                            const float* __restrict__ out_w, const float* __restrict__ out_b,
                            const float* __restrict__ fc2_w, const float* __restrict__ fc2_b,
                            float* __restrict__ ws) {
  const int gslot = blockIdx.x;
  const int g = gslot ? 3 : 1;
  const int t = threadIdx.x;  // 256
  __shared__ float cw[HYP];
  __shared__ float ow2[HYP];
  if (t < HYP) {
    const float* fw = fc2_w + g * EMB * HYP;
    float s = 0.f;
    for (int e = 0; e < EMB; ++e) s += fw[e * HYP + t];
    cw[t] = s;
  }
  __syncthreads();
  if (t < HYP) {
    const float* ow = out_w + g * HYP * HYP;
    float s = 0.f;
    for (int h = 0; h < HYP; ++h) s += ow[h * HYP + t] * cw[h];
    ow2[t] = s;
  }
  __syncthreads();
  float* wsg = ws + gslot * 1024;
  const float* qwv = qkv_w + (size_t)(g * 3 + 2) * HYP * HYP;  // V rows (256..383)
  for (int o = t; o < NHEADS * HYP; o += 256) {
    int hh = o >> 7, h2 = o & 127;
    float s = 0.f;
    for (int d = 0; d < HD; ++d)
      s += qwv[(hh * HD + d) * HYP + h2] * ow2[hh * HD + d];
    wsg[o] = s;
  }
  if (t < NHEADS) {
    const float* qbv = qkv_b + g * 3 * HYP + 2 * HYP;
    float s = 0.f;
    for (int d = 0; d < HD; ++d) s += qbv[t * HD + d] * ow2[t * HD + d];
    wsg[512 + t] = s;
  }
  if (t == 0) {
    const float* ob = out_b + g * HYP;
    float oc = 0.f;
    for (int h = 0; h < HYP; ++h) oc += ob[h] * cw[h];
    const float* fb = fc2_b + g * EMB;
    float cb = 0.f;
    for (int e = 0; e < EMB; ++e) cb += fb[e];
    wsg[516] = oc + cb;
  }
}

__device__ __forceinline__ void mm_tile(const float (*__restrict__ XT)[36],
                                        const float* __restrict__ W, int wld, int K,
                                        int n0, int h0, float acc[4][4]) {
  for (int kk = 0; kk < K; kk += 4) {
    float4 ev[4], wv[4];
#pragma unroll
    for (int i = 0; i < 4; ++i) ev[i] = *(const float4*)&XT[kk + i][n0];
#pragma unroll
    for (int j = 0; j < 4; ++j) wv[j] = *(const float4*)&W[(h0 + j) * wld + kk];
    const float* ef = (const float*)ev;
    const float* wf = (const float*)wv;
#pragma unroll
    for (int i = 0; i < 4; ++i)
#pragma unroll
      for (int n = 0; n < 4; ++n)
#pragma unroll
        for (int j = 0; j < 4; ++j)
          acc[n][j] = fmaf(ef[i * 4 + n], wf[j * 4 + i], acc[n][j]);
  }
}

__global__ __launch_bounds__(256, 2)
void mixer_kernel(const float* __restrict__ agent_qs,
                  const float* __restrict__ entities,
                  const int* __restrict__ entity_mask,
                  const float* __restrict__ fc1_w,
                  const float* __restrict__ fc1_b,
                  const float* __restrict__ qkv_w,
                  const float* __restrict__ qkv_b,
                  const float* __restrict__ ws,
                  float* __restrict__ out) {
  const int b = blockIdx.x;
  const int t = threadIdx.x;
  const int ht = t & 31, nt = t >> 5;
  const int h0 = ht * 4, n0 = nt * 4;

  __shared__ __align__(16) float sET[ED][36];    // E^T  [k][ent]
  __shared__ __align__(16) float sX1T[HYP][36];  // x1^T [h][ent]
  __shared__ __align__(16) float sKT[HYP][36];   // k^T  [h][ent]
  __shared__ __align__(16) float sQ[N_AGENTS][HYP];
  __shared__ float sVP[NHEADS][NE];
  __shared__ int sM[NE];
  __shared__ float sPart[NHEADS][N_AGENTS];
  __shared__ float gS[2];

  const float* E = entities + (size_t)b * NE * ED;
  for (int i = t; i < NE * ED; i += 256) {
    sET[i & 63][i >> 6] = E[i];
  }
  if (t < NE) sM[t] = entity_mask[b * NE + t];
  __syncthreads();

  for (int gi = 0; gi < 2; ++gi) {
    const int g = gi ? 3 : 1;
    const float* wsg = ws + gi * 1024;

    // ---- stage 1: x1 = relu(E @ fc1^T + fc1_b)  (32 x 128, K=64) ----
    {
      const float* W1 = fc1_w + (size_t)g * HYP * ED;
      float acc[4][4] = {};
      mm_tile(sET, W1, ED, ED, n0, h0, acc);
      const float* b1 = fc1_b + g * HYP;
#pragma unroll
      for (int j = 0; j < 4; ++j) {
        float bb = b1[h0 + j];
#pragma unroll
        for (int n = 0; n < 4; ++n) {
          float v = acc[n][j] + bb;
          sX1T[h0 + j][n0 + n] = v > 0.f ? v : 0.f;
        }
      }
    }
    __syncthreads();

    // ---- stage 2a: K = x1 @ Wk^T + bk  (32 x 128, K=128) ----
    {
      const float* Wk = qkv_w + (size_t)(g * 3 + 1) * HYP * HYP;
      const float* bk = qkv_b + g * 3 * HYP + HYP;
      float acc[4][4] = {};
      mm_tile(sX1T, Wk, HYP, HYP, n0, h0, acc);
#pragma unroll
      for (int j = 0; j < 4; ++j) {
        float bb = bk[h0 + j];
#pragma unroll
        for (int n = 0; n < 4; ++n) sKT[h0 + j][n0 + n] = acc[n][j] + bb;
      }
    }
    // ---- stage 2b: Q rows for the 8 agents (8 x 128, K=128) ----
    {
      const int a = nt;  // 0..7
      const float* Wq = qkv_w + (size_t)g * 3 * HYP * HYP;
      const float* bq = qkv_b + g * 3 * HYP;
      float acc4[4] = {};
      for (int kk = 0; kk < HYP; kk += 4) {
        float e[4];
#pragma unroll
        for (int i = 0; i < 4; ++i) e[i] = sX1T[kk + i][a];
        float4 wv[4];
#pragma unroll
        for (int j = 0; j < 4; ++j) wv[j] = *(const float4*)&Wq[(h0 + j) * HYP + kk];
        const float* wf = (const float*)wv;
#pragma unroll
        for (int i = 0; i < 4; ++i)
#pragma unroll
          for (int j = 0; j < 4; ++j) acc4[j] = fmaf(e[i], wf[j * 4 + i], acc4[j]);
      }
#pragma unroll
      for (int j = 0; j < 4; ++j) sQ[a][h0 + j] = acc4[j] + bq[h0 + j];
    }
    // ---- stage 2c: vproj[hh][ent] = x1[ent] . vw2[hh] + vb2[hh] ----
    if (t < NHEADS * NE) {
      int hh = t >> 5, ke = t & 31;
      float s = wsg[512 + hh];
      for (int h2 = 0; h2 < HYP; ++h2)
        s = fmaf(sX1T[h2][ke], wsg[hh * HYP + h2], s);
      sVP[hh][ke] = s;
    }
    __syncthreads();

    // ---- stage 3: masked attention, softmax, and w . vproj reduction ----
    {
      const int hh = t >> 6;   // wave = head
      const int lane = t & 63;
      const int ke = lane & 31;
      const int ah = lane >> 5;
      const float vp = sVP[hh][ke];
      const int kact = (sM[ke] == 0);
#pragma unroll
      for (int ap = 0; ap < 4; ++ap) {
        const int a = ap * 2 + ah;
        float lg = 0.f;
#pragma unroll
        for (int d = 0; d < HD; ++d)
          lg = fmaf(sQ[a][hh * HD + d], sKT[hh * HD + d][ke], lg);
        const bool act = kact && (sM[a] == 0);  // attn_mask==0 -> attended
        lg = act ? lg * 0.17677669529663687f : -1e9f;
        float m = lg;
        for (int o = 16; o; o >>= 1) m = fmaxf(m, __shfl_xor(m, o, 32));
        float p = __expf(lg - m);
        float sum = p;
        for (int o = 16; o; o >>= 1) sum += __shfl_xor(sum, o, 32);
        float w = act ? p / sum : 0.f;  // also covers all-masked row -> 0
        float c = w * vp;
        for (int o = 16; o; o >>= 1) c += __shfl_xor(c, o, 32);
        if (ke == 0) sPart[hh][a] = c;
      }
    }
    __syncthreads();
    if (t == 0) {
      const float cg = wsg[516];
      float S = 0.f;
      for (int a = 0; a < N_AGENTS; ++a)
        if (sM[a] == 0)
          S += sPart[0][a] + sPart[1][a] + sPart[2][a] + sPart[3][a] + cg;
      gS[gi] = S;
    }
    __syncthreads();
  }

  if (t == 0) {
    const float* qs = agent_qs + (size_t)b * N_AGENTS;
    float q = 0.f;
    for (int a = 0; a < N_AGENTS; ++a) q += qs[a];
    out[b] = q + gS[0] * 0.125f + gS[1] * (1.f / 256.f);
  }
}

extern "C" void kernel_launch(void* const* d_in, const int* in_sizes, int n_in,
                              void* d_out, int out_size, void* d_ws, size_t ws_size,
                              hipStream_t stream) {
  const float* agent_qs = (const float*)d_in[0];
  const float* entities = (const float*)d_in[1];
  const int* emask = (const int*)d_in[2];
  const float* fc1_w = (const float*)d_in[3];
  const float* fc1_b = (const float*)d_in[4];
  const float* qkv_w = (const float*)d_in[5];
  const float* qkv_b = (const float*)d_in[6];
  const float* out_w = (const float*)d_in[7];
  const float* out_b = (const float*)d_in[8];
  const float* fc2_w = (const float*)d_in[9];
  const float* fc2_b = (const float*)d_in[10];
  float* out = (float*)d_out;
  float* ws = (float*)d_ws;

  prep_kernel<<<2, 256, 0, stream>>>(qkv_w, qkv_b, out_w, out_b, fc2_w, fc2_b, ws);
  mixer_kernel<<<NB, 256, 0, stream>>>(agent_qs, entities, emask, fc1_w, fc1_b,
                                       qkv_w, qkv_b, ws, out);
}

// Round 2
// 169.346 us; speedup vs baseline: 7.6579x; 7.6579x over previous
//
#include <hip/hip_runtime.h>
#include <math.h>

#define BPB 4
#define NBLK 1024  // 4096 / BPB

typedef short short8 __attribute__((ext_vector_type(8)));
typedef float f32x4 __attribute__((ext_vector_type(4)));

__device__ __forceinline__ unsigned short f2bf(float x) {
  unsigned int u = __float_as_uint(x);
  u += 0x7fffu + ((u >> 16) & 1u);
  return (unsigned short)(u >> 16);
}
__device__ __forceinline__ float bf2f(unsigned int lo16) {
  return __uint_as_float(lo16 << 16);
}
// [16 rows][32 k] bf16 tile (1KB), XOR-swizzled 16B granules (2-way max conflict)
__device__ __forceinline__ int tile_addr(int r, int k) {
  int g = k >> 3;
  int p = (g ^ ((r >> 1) & 3)) & 3;
  return r * 32 + p * 8 + (k & 7);
}
// row-major [rows][128] bf16, rotate-XOR swizzle (injective over 8 rows)
__device__ __forceinline__ int rm_addr(int r, int k) {
  int g = k >> 3;
  int r3 = r & 7;
  int rot = ((r3 << 2) | (r3 >> 1)) & 7;
  int p = (g & 8) | ((g & 7) ^ rot);
  return r * 128 + p * 8 + (k & 7);
}

// ---- prep_w: convert W1/Wk/Wq (groups 1,3) to bf16 swizzled tiles in ws ----
// ws bf16 layout (shorts): per gi (stride 40960): W1 [0,8192), Wk [8192,24576), Wq [24576,40960)
__global__ void prep_w(const float* __restrict__ fc1_w, const float* __restrict__ qkv_w,
                       unsigned short* __restrict__ wbf) {
  int gid = blockIdx.x * 256 + threadIdx.x;
  for (int o = gid * 2; o < gid * 2 + 2; ++o) {
    float v; int dst;
    if (o < 16384) {  // W1: [2][128][64]
      int gi = o >> 13, rem = o & 8191, n = rem >> 6, k = rem & 63;
      int g = gi ? 3 : 1;
      v = fc1_w[((g << 7) + n) * 64 + k];
      dst = gi * 40960 + ((n >> 4) * 2 + (k >> 5)) * 512 + tile_addr(n & 15, k & 31);
    } else if (o < 49152) {  // Wk: [2][128][128]
      int o2 = o - 16384;
      int gi = o2 >> 14, rem = o2 & 16383, n = rem >> 7, k = rem & 127;
      int g = gi ? 3 : 1;
      v = qkv_w[((g * 384 + 128 + n) << 7) + k];
      dst = gi * 40960 + 8192 + ((n >> 4) * 4 + (k >> 5)) * 512 + tile_addr(n & 15, k & 31);
    } else {  // Wq
      int o2 = o - 49152;
      int gi = o2 >> 14, rem = o2 & 16383, n = rem >> 7, k = rem & 127;
      int g = gi ? 3 : 1;
      v = qkv_w[((g * 384 + n) << 7) + k];
      dst = gi * 40960 + 24576 + ((n >> 4) * 4 + (k >> 5)) * 512 + tile_addr(n & 15, k & 31);
    }
    wbf[dst] = f2bf(v);
  }
}

// ---- prep_misc: vw2/vb2/const per group (verified round-1 logic) ----
__global__ void prep_misc(const float* __restrict__ qkv_w, const float* __restrict__ qkv_b,
                          const float* __restrict__ out_w, const float* __restrict__ out_b,
                          const float* __restrict__ fc2_w, const float* __restrict__ fc2_b,
                          float* __restrict__ wsf) {
  const int gslot = blockIdx.x;
  const int g = gslot ? 3 : 1;
  const int t = threadIdx.x;
  __shared__ float cw[128];
  __shared__ float ow2[128];
  if (t < 128) {
    const float* fw = fc2_w + g * 32 * 128;
    float s = 0.f;
    for (int e = 0; e < 32; ++e) s += fw[e * 128 + t];
    cw[t] = s;
  }
  __syncthreads();
  if (t < 128) {
    const float* ow = out_w + g * 128 * 128;
    float s = 0.f;
    for (int h = 0; h < 128; ++h) s += ow[h * 128 + t] * cw[h];
    ow2[t] = s;
  }
  __syncthreads();
  float* wsg = wsf + gslot * 1024;
  const float* qwv = qkv_w + (size_t)(g * 3 + 2) * 128 * 128;
  for (int o = t; o < 512; o += 256) {
    int hh = o >> 7, h2 = o & 127;
    float s = 0.f;
    for (int d = 0; d < 32; ++d) s += qwv[(hh * 32 + d) * 128 + h2] * ow2[hh * 32 + d];
    wsg[o] = s;
  }
  if (t < 4) {
    const float* qbv = qkv_b + g * 384 + 256;
    float s = 0.f;
    for (int d = 0; d < 32; ++d) s += qbv[t * 32 + d] * ow2[t * 32 + d];
    wsg[512 + t] = s;
  }
  if (t == 0) {
    const float* ob = out_b + g * 128;
    float oc = 0.f;
    for (int h = 0; h < 128; ++h) oc += ob[h] * cw[h];
    const float* fb = fc2_b + g * 32;
    float cb = 0.f;
    for (int e = 0; e < 32; ++e) cb += fb[e];
    wsg[516] = oc + cb;
  }
}

__global__ __launch_bounds__(512, 1)
void mixer(const float* __restrict__ agent_qs,
           const float* __restrict__ entities,
           const int* __restrict__ emask,
           const float* __restrict__ fc1_b,
           const float* __restrict__ qkv_b,
           const unsigned short* __restrict__ wbf,
           const float* __restrict__ wsf,
           float* __restrict__ out) {
  __shared__ __align__(16) unsigned short sW[24576];   // 48KB: W1 [0,8192), Wk/Wq [8192,24576)
  __shared__ __align__(16) unsigned short sEK[16384];  // E tiles then K rm-storage (per b 4096)
  __shared__ __align__(16) unsigned short sX1[16384];  // x1 tiles (per b 4096: [mt2][kc4][512])
  __shared__ __align__(16) unsigned short sQ[4096];    // per b: 8x128 rm
  __shared__ __align__(16) float sVW[1024];            // vw2 + vb2 + const
  __shared__ float sVP[BPB][4][32];
  __shared__ int sMm[BPB * 32];
  __shared__ float sS[8];

  const int t = threadIdx.x;
  const int lane = t & 63;
  const int w = t >> 6;
  const int bb0 = blockIdx.x * BPB;

  if (t < BPB * 32) sMm[t] = emask[bb0 * 32 + t];

  float wreg[4][2][4];

  for (int gi = 0; gi < 2; ++gi) {
    const int g = gi ? 3 : 1;
    __syncthreads();
    // ---- stage: W1+Wk copy (3072 uint4), vw2 (256 float4), E (2048 float4 -> bf16 tiles) ----
    {
      const uint4* src = (const uint4*)(wbf + gi * 40960);
      uint4* dst = (uint4*)sW;
#pragma unroll
      for (int i = 0; i < 6; ++i) dst[i * 512 + t] = src[i * 512 + t];
      if (t < 256) ((float4*)sVW)[t] = ((const float4*)(wsf + gi * 1024))[t];
      const float4* Eg = (const float4*)(entities) + (size_t)bb0 * 512;
#pragma unroll
      for (int i = 0; i < 4; ++i) {
        int f4 = i * 512 + t;
        float4 v = Eg[f4];
        int k4 = f4 & 15, e = (f4 >> 4) & 31, bbi = f4 >> 9;
        int k = k4 * 4;
        int addr = bbi * 2048 + ((e >> 4) * 2 + (k >> 5)) * 512 + tile_addr(e & 15, k & 31);
        uint2 pk;
        pk.x = (unsigned)f2bf(v.x) | ((unsigned)f2bf(v.y) << 16);
        pk.y = (unsigned)f2bf(v.z) | ((unsigned)f2bf(v.w) << 16);
        *(uint2*)&sEK[addr] = pk;
      }
    }
    __syncthreads();
    // ---- x1 = relu(E @ W1^T + b1): wave w -> m-tile w ----
    {
      const int b = w >> 1, mtl = w & 1;
      const int r = lane & 15, kg = lane >> 4;
      f32x4 acc[8];
#pragma unroll
      for (int nt = 0; nt < 8; ++nt) acc[nt] = {0.f, 0.f, 0.f, 0.f};
#pragma unroll
      for (int kc = 0; kc < 2; ++kc) {
        short8 af = *(const short8*)&sEK[b * 2048 + (mtl * 2 + kc) * 512 + tile_addr(r, kg * 8)];
#pragma unroll
        for (int nt = 0; nt < 8; ++nt) {
          short8 bf = *(const short8*)&sW[(nt * 2 + kc) * 512 + tile_addr(r, kg * 8)];
          acc[nt] = __builtin_amdgcn_mfma_f32_16x16x32_bf16(af, bf, acc[nt], 0, 0, 0);
        }
      }
      const float* b1 = fc1_b + g * 128;
#pragma unroll
      for (int nt = 0; nt < 8; ++nt) {
        int h = nt * 16 + r;
        float bias = b1[h];
        int kc = h >> 5;
#pragma unroll
        for (int reg = 0; reg < 4; ++reg) {
          int rr = kg * 4 + reg;
          float v = acc[nt][reg] + bias;
          v = v > 0.f ? v : 0.f;
          sX1[b * 4096 + (mtl * 4 + kc) * 512 + tile_addr(rr, h & 31)] = f2bf(v);
        }
      }
    }
    __syncthreads();
    // ---- K = x1 @ Wk^T + bk: wave w -> m-tile w; store rm-swizzled over E region ----
    {
      const int b = w >> 1, mtl = w & 1;
      const int r = lane & 15, kg = lane >> 4;
      f32x4 acc[8];
#pragma unroll
      for (int nt = 0; nt < 8; ++nt) acc[nt] = {0.f, 0.f, 0.f, 0.f};
#pragma unroll
      for (int kc = 0; kc < 4; ++kc) {
        short8 af = *(const short8*)&sX1[b * 4096 + (mtl * 4 + kc) * 512 + tile_addr(r, kg * 8)];
#pragma unroll
        for (int nt = 0; nt < 8; ++nt) {
          short8 bf = *(const short8*)&sW[8192 + (nt * 4 + kc) * 512 + tile_addr(r, kg * 8)];
          acc[nt] = __builtin_amdgcn_mfma_f32_16x16x32_bf16(af, bf, acc[nt], 0, 0, 0);
        }
      }
      const float* bk = qkv_b + g * 384 + 128;
#pragma unroll
      for (int nt = 0; nt < 8; ++nt) {
        int h = nt * 16 + r;
        float bias = bk[h];
#pragma unroll
        for (int reg = 0; reg < 4; ++reg) {
          int ent = mtl * 16 + kg * 4 + reg;
          sEK[b * 4096 + rm_addr(ent, h)] = f2bf(acc[nt][reg] + bias);
        }
      }
    }
    __syncthreads();
    // ---- overwrite Wk region with Wq (2048 uint4) ----
    {
      const uint4* src = (const uint4*)(wbf + gi * 40960 + 24576);
      uint4* dst = (uint4*)(sW + 8192);
#pragma unroll
      for (int i = 0; i < 4; ++i) dst[i * 512 + t] = src[i * 512 + t];
    }
    __syncthreads();
    // ---- Q = x1_agents @ Wq^T + bq: wave w: m-tile w>>2 (2 b's x 8 agents), nt pair w&3 ----
    {
      const int mt = w >> 2;
      const int r = lane & 15, kg = lane >> 4;
      const int b_rd = mt * 2 + (r >> 3);
      f32x4 acc[2];
      acc[0] = {0.f, 0.f, 0.f, 0.f};
      acc[1] = {0.f, 0.f, 0.f, 0.f};
#pragma unroll
      for (int kc = 0; kc < 4; ++kc) {
        short8 af = *(const short8*)&sX1[b_rd * 4096 + kc * 512 + tile_addr(r & 7, kg * 8)];
#pragma unroll
        for (int j = 0; j < 2; ++j) {
          int nt = (w & 3) * 2 + j;
          short8 bf = *(const short8*)&sW[8192 + (nt * 4 + kc) * 512 + tile_addr(r, kg * 8)];
          acc[j] = __builtin_amdgcn_mfma_f32_16x16x32_bf16(af, bf, acc[j], 0, 0, 0);
        }
      }
      const float* bq = qkv_b + g * 384;
#pragma unroll
      for (int j = 0; j < 2; ++j) {
        int nt = (w & 3) * 2 + j;
        int h = nt * 16 + r;
        float bias = bq[h];
#pragma unroll
        for (int reg = 0; reg < 4; ++reg) {
          int rr = kg * 4 + reg;
          int b_st = mt * 2 + (rr >> 3);
          sQ[b_st * 1024 + rm_addr(rr & 7, h)] = f2bf(acc[j][reg] + bias);
        }
      }
    }
    __syncthreads();
    // ---- phase P: waves 0-3 logits+softmax (b=w); waves 4-7 vproj (b=w-4) ----
    if (w < 4) {
      const int b = w;
      const int cl = lane & 15, kg = lane >> 4;
      bool ea0 = (sMm[b * 32 + cl] == 0);
      bool ea1 = (sMm[b * 32 + 16 + cl] == 0);
      bool aa[4];
#pragma unroll
      for (int reg = 0; reg < 4; ++reg) aa[reg] = (sMm[b * 32 + ((kg * 4 + reg) & 7)] == 0);
#pragma unroll
      for (int hh = 0; hh < 4; ++hh) {
        short8 af = *(const short8*)&sQ[b * 1024 + rm_addr(lane & 7, hh * 32 + kg * 8)];
        f32x4 d[2];
#pragma unroll
        for (int nt = 0; nt < 2; ++nt) {
          f32x4 z = {0.f, 0.f, 0.f, 0.f};
          short8 bf = *(const short8*)&sEK[b * 4096 + rm_addr(nt * 16 + cl, hh * 32 + kg * 8)];
          d[nt] = __builtin_amdgcn_mfma_f32_16x16x32_bf16(af, bf, z, 0, 0, 0);
        }
#pragma unroll
        for (int reg = 0; reg < 4; ++reg) {
          float lg0 = (ea0 && aa[reg]) ? d[0][reg] * 0.17677669529663687f : -1e30f;
          float lg1 = (ea1 && aa[reg]) ? d[1][reg] * 0.17677669529663687f : -1e30f;
          float m = fmaxf(lg0, lg1);
          for (int o = 8; o; o >>= 1) m = fmaxf(m, __shfl_xor(m, o, 16));
          float p0 = lg0 > -1e29f ? __expf(lg0 - m) : 0.f;
          float p1 = lg1 > -1e29f ? __expf(lg1 - m) : 0.f;
          float s = p0 + p1;
          for (int o = 8; o; o >>= 1) s += __shfl_xor(s, o, 16);
          float inv = s > 0.f ? 1.f / s : 0.f;
          wreg[hh][0][reg] = p0 * inv;
          wreg[hh][1][reg] = p1 * inv;
        }
      }
    } else {
      const int b = w - 4;
      const int e = lane & 31;
      const int hh0 = (lane >> 5) * 2;
      const int mt = e >> 4, r = e & 15;
      float a0 = sVW[512 + hh0];
      float a1 = sVW[512 + hh0 + 1];
#pragma unroll
      for (int kc = 0; kc < 4; ++kc) {
#pragma unroll
        for (int gg = 0; gg < 4; ++gg) {
          uint4 u = *(const uint4*)&sX1[b * 4096 + (mt * 4 + kc) * 512 + tile_addr(r, gg * 8)];
          int kb = kc * 32 + gg * 8;
          const float* w0 = &sVW[hh0 * 128 + kb];
          const float* w1 = &sVW[(hh0 + 1) * 128 + kb];
          float x0 = bf2f(u.x & 0xffffu), x1v = bf2f(u.x >> 16);
          float x2 = bf2f(u.y & 0xffffu), x3v = bf2f(u.y >> 16);
          float x4 = bf2f(u.z & 0xffffu), x5v = bf2f(u.z >> 16);
          float x6 = bf2f(u.w & 0xffffu), x7v = bf2f(u.w >> 16);
          a0 = fmaf(x0, w0[0], a0); a0 = fmaf(x1v, w0[1], a0);
          a0 = fmaf(x2, w0[2], a0); a0 = fmaf(x3v, w0[3], a0);
          a0 = fmaf(x4, w0[4], a0); a0 = fmaf(x5v, w0[5], a0);
          a0 = fmaf(x6, w0[6], a0); a0 = fmaf(x7v, w0[7], a0);
          a1 = fmaf(x0, w1[0], a1); a1 = fmaf(x1v, w1[1], a1);
          a1 = fmaf(x2, w1[2], a1); a1 = fmaf(x3v, w1[3], a1);
          a1 = fmaf(x4, w1[4], a1); a1 = fmaf(x5v, w1[5], a1);
          a1 = fmaf(x6, w1[6], a1); a1 = fmaf(x7v, w1[7], a1);
        }
      }
      sVP[b][hh0][e] = a0;
      sVP[b][hh0 + 1][e] = a1;
    }
    __syncthreads();
    // ---- final per-b reduction: Sum_{a,e,h} w * vp (+ const * activeCount) ----
    if (w < 4) {
      const int b = w;
      const int cl = lane & 15;
      float c = 0.f;
#pragma unroll
      for (int hh = 0; hh < 4; ++hh) {
        float vp0 = sVP[b][hh][cl];
        float vp1 = sVP[b][hh][16 + cl];
        float s0 = wreg[hh][0][0] + wreg[hh][0][1] + wreg[hh][0][2] + wreg[hh][0][3];
        float s1 = wreg[hh][1][0] + wreg[hh][1][1] + wreg[hh][1][2] + wreg[hh][1][3];
        c = fmaf(vp0, s0, fmaf(vp1, s1, c));
      }
      for (int o = 16; o; o >>= 1) c += __shfl_xor(c, o, 32);
      if (lane == 0) {
        int cnt = 0;
        for (int a = 0; a < 8; ++a) cnt += (sMm[b * 32 + a] == 0);
        sS[gi * 4 + b] = c + sVW[516] * (float)cnt;
      }
    }
  }
  __syncthreads();
  if (t < BPB) {
    const float* qs = agent_qs + (size_t)(bb0 + t) * 8;
    float q = 0.f;
    for (int a = 0; a < 8; ++a) q += qs[a];
    out[bb0 + t] = q + sS[t] * 0.125f + sS[4 + t] * (1.f / 256.f);
  }
}

extern "C" void kernel_launch(void* const* d_in, const int* in_sizes, int n_in,
                              void* d_out, int out_size, void* d_ws, size_t ws_size,
                              hipStream_t stream) {
  const float* agent_qs = (const float*)d_in[0];
  const float* entities = (const float*)d_in[1];
  const int* emask = (const int*)d_in[2];
  const float* fc1_w = (const float*)d_in[3];
  const float* fc1_b = (const float*)d_in[4];
  const float* qkv_w = (const float*)d_in[5];
  const float* qkv_b = (const float*)d_in[6];
  const float* out_w = (const float*)d_in[7];
  const float* out_b = (const float*)d_in[8];
  const float* fc2_w = (const float*)d_in[9];
  const float* fc2_b = (const float*)d_in[10];
  float* out = (float*)d_out;
  unsigned short* wbf = (unsigned short*)d_ws;
  float* wsf = (float*)((char*)d_ws + 163840);

  prep_w<<<160, 256, 0, stream>>>(fc1_w, qkv_w, wbf);
  prep_misc<<<2, 256, 0, stream>>>(qkv_w, qkv_b, out_w, out_b, fc2_w, fc2_b, wsf);
  mixer<<<NBLK, 512, 0, stream>>>(agent_qs, entities, emask, fc1_b, qkv_b, wbf, wsf, out);
}